// Round 1
// 424.411 us; speedup vs baseline: 1.1267x; 1.1267x over previous
//
#include <hip/hip_runtime.h>

typedef _Float16 half8 __attribute__((ext_vector_type(8)));
typedef _Float16 hv4 __attribute__((ext_vector_type(4)));
typedef float fv4 __attribute__((ext_vector_type(4)));

typedef __attribute__((address_space(3))) unsigned lds_u32;
typedef const __attribute__((address_space(1))) unsigned glb_u32;

// async global->LDS, 16B per lane; dst is wave-uniform base, HW adds lane*16B
__device__ __forceinline__ void gll16(const void* g, void* l) {
  __builtin_amdgcn_global_load_lds((glb_u32*)g, (lds_u32*)l, 16, 0, 0);
}

// ---------------------------------------------------------------- LayerNorm
__device__ __forceinline__ void ln_body(const float* __restrict__ in, const float* __restrict__ g,
                                        const float* __restrict__ bb, _Float16* __restrict__ out,
                                        int ncols, int row) {
  __shared__ float sm[8];
  int t = threadIdx.x;
  const float* rp = in + (size_t)row * ncols;
  int nv = ncols >> 10;
  fv4 v[2];
  float s1 = 0.f, s2 = 0.f;
#pragma unroll
  for (int c = 0; c < 2; ++c)
    if (c < nv) {
      v[c] = *(const fv4*)(rp + c * 1024 + t * 4);
#pragma unroll
      for (int j = 0; j < 4; ++j) { s1 += v[c][j]; s2 += v[c][j] * v[c][j]; }
    }
#pragma unroll
  for (int off = 32; off > 0; off >>= 1) { s1 += __shfl_xor(s1, off, 64); s2 += __shfl_xor(s2, off, 64); }
  int w = t >> 6;
  if ((t & 63) == 0) { sm[w] = s1; sm[4 + w] = s2; }
  __syncthreads();
  s1 = sm[0] + sm[1] + sm[2] + sm[3];
  s2 = sm[4] + sm[5] + sm[6] + sm[7];
  float inv = 1.0f / (float)ncols;
  float mu = s1 * inv;
  float var = s2 * inv - mu * mu;
  float rstd = rsqrtf(var + 1e-5f);
#pragma unroll
  for (int c = 0; c < 2; ++c)
    if (c < nv) {
      int col = c * 1024 + t * 4;
      fv4 gg = *(const fv4*)(g + col);
      fv4 bv = *(const fv4*)(bb + col);
      hv4 o;
#pragma unroll
      for (int j = 0; j < 4; ++j) o[j] = (_Float16)(((v[c][j] - mu) * rstd) * gg[j] + bv[j]);
      *(hv4*)(out + (size_t)row * ncols + col) = o;
    }
}

// merged: blocks [0,2048) -> hidden LN (2048 cols), [2048,4096) -> memory LN (1024 cols)
__global__ __launch_bounds__(256) void ln_all(const float* __restrict__ hid,
                                              const float* __restrict__ mem,
                                              const float* __restrict__ gs, const float* __restrict__ bs,
                                              const float* __restrict__ gm, const float* __restrict__ bm,
                                              _Float16* __restrict__ oh, _Float16* __restrict__ om) {
  int b = blockIdx.x;
  if (b < 2048) ln_body(hid, gs, bs, oh, 2048, b);
  else ln_body(mem, gm, bm, om, 1024, b - 2048);
}

// ---------------------------------------------------------------- merged fp32 -> fp16 casts
// block ranges: [0,2048) Wq, [2048,3072) Wk, [3072,4096) Wv, [4096,6144) Wo
__global__ __launch_bounds__(256) void cast_all(const float* __restrict__ s0, _Float16* __restrict__ d0,
                                                const float* __restrict__ s1, _Float16* __restrict__ d1,
                                                const float* __restrict__ s2, _Float16* __restrict__ d2,
                                                const float* __restrict__ s3, _Float16* __restrict__ d3) {
  int b = blockIdx.x;
  const float* s;
  _Float16* d;
  int off;
  if (b < 2048) { s = s0; d = d0; off = b; }
  else if (b < 3072) { s = s1; d = d1; off = b - 2048; }
  else if (b < 4096) { s = s2; d = d2; off = b - 3072; }
  else { s = s3; d = d3; off = b - 4096; }
  int i = (off * 256 + threadIdx.x) << 2;
  fv4 f = *(const fv4*)(s + i);
  hv4 h;
#pragma unroll
  for (int j = 0; j < 4; ++j) h[j] = (_Float16)f[j];
  *(hv4*)(d + i) = h;
}

// ---------------------------------------------------------------- sum ns partials -> fp16
__global__ __launch_bounds__(256) void reduce_split(const float* __restrict__ parts, int ns,
                                                    long long stride,
                                                    _Float16* __restrict__ hi, int n) {
  int i = (blockIdx.x * 256 + threadIdx.x) << 2;
  if (i < n) {
    fv4 s = *(const fv4*)(parts + i);
    for (int j = 1; j < ns; ++j) {
      fv4 v = *(const fv4*)(parts + (size_t)j * stride + i);
      s += v;
    }
    hv4 h;
#pragma unroll
    for (int j = 0; j < 4; ++j) h[j] = (_Float16)s[j];
    *(hv4*)(hi + i) = h;
  }
}

// ---------------------------------------------------------------- entmax-1.5: tau solve only
// One wave per score row (2048 fp16). Michelot exact support iteration from superset
// S0={x>-1}; after count <=512 survivors are compacted to LDS and iterated cheaply.
// Outputs c = m/2 + tau per row so that w = (max(0, s/2 - c))^2 (applied in the w@V GEMM).
__global__ __launch_bounds__(256) void entmax_c(const _Float16* __restrict__ scores,
                                                float* __restrict__ crow) {
  __shared__ float comp[4][512];
  int wid = threadIdx.x >> 6;
  int row = blockIdx.x * 4 + wid;
  int l = threadIdx.x & 63;
  unsigned long long lmask = (1ull << l) - 1ull;
  const half8* sp = (const half8*)(scores + (size_t)row * 2048);
  half8 hx[4];
#pragma unroll
  for (int i = 0; i < 4; ++i) hx[i] = sp[i * 64 + l];
  fv4 x[8];
#pragma unroll
  for (int i = 0; i < 4; ++i)
#pragma unroll
    for (int j = 0; j < 8; ++j) x[i * 2 + (j >> 2)][j & 3] = (float)hx[i][j];
  float m = x[0][0];
#pragma unroll
  for (int i = 0; i < 8; ++i)
#pragma unroll
    for (int j = 0; j < 4; ++j) m = fmaxf(m, x[i][j]);
#pragma unroll
  for (int off = 32; off > 0; off >>= 1) m = fmaxf(m, __shfl_xor(m, off, 64));
#pragma unroll
  for (int i = 0; i < 8; ++i)
#pragma unroll
    for (int j = 0; j < 4; ++j) x[i][j] = (x[i][j] - m) * 0.5f;

  float tau = -1.0f;
  bool fixed = false;
  int cnti = 2048;
  // phase 1: full-register scans until support fits in the compaction buffer
  for (int it = 0; it < 6 && !fixed; ++it) {
    float s1 = 0.f, s2 = 0.f;
    cnti = 0;
#pragma unroll
    for (int i = 0; i < 8; ++i)
#pragma unroll
      for (int j = 0; j < 4; ++j) {
        bool a = x[i][j] > tau;
        cnti += (int)__builtin_popcountll(__ballot(a));
        float sel = a ? x[i][j] : 0.f;
        s1 += sel;
        s2 = fmaf(sel, sel, s2);
      }
#pragma unroll
    for (int off = 32; off > 0; off >>= 1) {
      s1 += __shfl_xor(s1, off, 64);
      s2 += __shfl_xor(s2, off, 64);
    }
    float cnt = (float)cnti;
    float mean = s1 / cnt;
    float ss = s2 - s1 * mean;
    float nt = mean - sqrtf(fmaxf((1.0f - ss) / cnt, 0.0f));
    if (nt == tau) fixed = true;
    else tau = nt;
    if (cnti <= 512) break;
  }
  if (!fixed) {
    if (cnti <= 512) {
      // compact survivors {x > tau} into LDS (count <= cnti <= 512)
      int base = 0;
#pragma unroll
      for (int i = 0; i < 8; ++i)
#pragma unroll
        for (int j = 0; j < 4; ++j) {
          bool a = x[i][j] > tau;
          unsigned long long mk = __ballot(a);
          if (a) comp[wid][base + (int)__builtin_popcountll(mk & lmask)] = x[i][j];
          base += (int)__builtin_popcountll(mk);
        }
      float y[8];
#pragma unroll
      for (int r = 0; r < 8; ++r) {
        int idx = r * 64 + l;
        y[r] = (idx < base) ? comp[wid][idx] : -2.0f;  // sentinel < -1 <= tau
      }
      for (int it = 0; it < 10 && !fixed; ++it) {
        float s1 = 0.f, s2 = 0.f;
        int c = 0;
#pragma unroll
        for (int r = 0; r < 8; ++r) {
          bool a = y[r] > tau;
          c += (int)__builtin_popcountll(__ballot(a));
          float sel = a ? y[r] : 0.f;
          s1 += sel;
          s2 = fmaf(sel, sel, s2);
        }
#pragma unroll
        for (int off = 32; off > 0; off >>= 1) {
          s1 += __shfl_xor(s1, off, 64);
          s2 += __shfl_xor(s2, off, 64);
        }
        float cnt = (float)c;
        float mean = s1 / cnt;
        float ss = s2 - s1 * mean;
        float nt = mean - sqrtf(fmaxf((1.0f - ss) / cnt, 0.0f));
        if (nt == tau) fixed = true;
        else tau = nt;
      }
    } else {
      for (int it = 0; it < 8 && !fixed; ++it) {
        float s1 = 0.f, s2 = 0.f;
        int c = 0;
#pragma unroll
        for (int i = 0; i < 8; ++i)
#pragma unroll
          for (int j = 0; j < 4; ++j) {
            bool a = x[i][j] > tau;
            c += (int)__builtin_popcountll(__ballot(a));
            float sel = a ? x[i][j] : 0.f;
            s1 += sel;
            s2 = fmaf(sel, sel, s2);
          }
#pragma unroll
        for (int off = 32; off > 0; off >>= 1) {
          s1 += __shfl_xor(s1, off, 64);
          s2 += __shfl_xor(s2, off, 64);
        }
        float cnt = (float)c;
        float mean = s1 / cnt;
        float ss = s2 - s1 * mean;
        float nt = mean - sqrtf(fmaxf((1.0f - ss) / cnt, 0.0f));
        if (nt == tau) fixed = true;
        else tau = nt;
      }
    }
  }

  if (l == 0) crow[row] = 0.5f * m + tau;
}

// ---------------------------------------------------------------- generic NT GEMM
// C[M,N] = alpha * A[M,K] @ B[N,K]^T.  128x128 tile, 4 waves, 4x4 16x16x32 f16 MFMA.
// Double-buffered LDS: prefetch tile t+1 (async gll16) before consuming tile t;
// one barrier per k-step (T3 minimum 2-phase).
// AMODE 0: plain fp16 A.
// AMODE 1: A = raw fp16 scores; w = (max(0, s/2 - c))^2 applied AFTER the LDS frag
//          read (crow is row-constant, hoisted out of the k-loop). Staging stays async.
// nsplit>1: bx = ntile*nsplit + kchunk; partial fp32 out at C32 + ks*partStride.
// dual: bz selects job {B,outMode} vs {B2,outModeB}.
// outMode 0: fp16   1: fp32
struct GemmParams {
  const _Float16 *A, *B, *B2;
  const float* crow;
  _Float16 *C16, *C16b;
  float* C32;
  const float* log_beta;
  int K, lda, ldb;
  long long aSB, aSH, bSH;
  long long crowSB, crowSH;
  long long cSB, cSH, cOsR, cOsC;
  long long cOsRb, cOsCb;
  long long partStride;
  int alphaMode, outMode, outModeB, nsplit, dual;
  int gx, gy, swz;
};

template <int AMODE>
__device__ __forceinline__ void gemm_body(const GemmParams& p, int bx, int by, int bz) {
  __shared__ __align__(16) _Float16 As[2][128 * 32];
  __shared__ __align__(16) _Float16 Bs[2][128 * 32];
  int t = threadIdx.x;
  int m0 = by * 128;
  int n0, kbeg, kend, ks = 0;
  if (p.nsplit > 1) {
    ks = bx % p.nsplit;
    n0 = (bx / p.nsplit) * 128;
    int kl = p.K / p.nsplit;
    kbeg = ks * kl;
    kend = kbeg + kl;
  } else {
    n0 = bx * 128;
    kbeg = 0;
    kend = p.K;
  }
  int bidx, h, job = 0;
  if (p.dual) { job = bz; bidx = 0; h = 0; }
  else { bidx = bz >> 3; h = bz & 7; }
  const _Float16* pA = p.A + bidx * p.aSB + h * p.aSH;
  const _Float16* pB = (job ? p.B2 : p.B) + h * p.bSH;

  fv4 acc[4][4] = {};
  int wv = t >> 6, l = t & 63, quad = l >> 4, lr = l & 15;
  int wm = (wv >> 1) * 64, wn = (wv & 1) * 64;
  int rl = l >> 2, cl = (l & 3) * 8;  // lane row-in-16 / halves offset for staging

  float cr[4];
  if (AMODE == 1) {
    const float* pc = p.crow + bidx * p.crowSB + h * p.crowSH;
#pragma unroll
    for (int mi = 0; mi < 4; ++mi) cr[mi] = pc[m0 + wm + mi * 16 + lr];
  }

  auto STAGE = [&](int buf, int k0) {
#pragma unroll
    for (int v = 0; v < 2; ++v) {
      int rb = wv * 16 + v * 64;  // wave-uniform row base
      int r = rb + rl;
      gll16(pA + (size_t)(m0 + r) * p.lda + k0 + cl, &As[buf][rb * 32]);
      gll16(pB + (size_t)(n0 + r) * p.ldb + k0 + cl, &Bs[buf][rb * 32]);
    }
  };

  int nk = (kend - kbeg) >> 5;
  STAGE(0, kbeg);
  __syncthreads();  // tile 0 staged
  int cur = 0;
  for (int ti = 0; ti < nk; ++ti) {
    if (ti + 1 < nk) STAGE(cur ^ 1, kbeg + ((ti + 1) << 5));  // prefetch next tile
    half8 ah[4], bh[4];
#pragma unroll
    for (int mi = 0; mi < 4; ++mi) {
      half8 a = *(const half8*)&As[cur][(wm + mi * 16 + lr) * 32 + quad * 8];
      if (AMODE == 1) {
        half8 d = a * (_Float16)0.5f - (_Float16)cr[mi];  // v_pk_fma (scalar splat)
        d = __builtin_elementwise_max(d, (half8)(0));     // v_pk_max_f16
        a = d * d;                                        // v_pk_mul_f16
      }
      ah[mi] = a;
    }
#pragma unroll
    for (int ni = 0; ni < 4; ++ni)
      bh[ni] = *(const half8*)&Bs[cur][(wn + ni * 16 + lr) * 32 + quad * 8];
    __builtin_amdgcn_s_setprio(1);
#pragma unroll
    for (int mi = 0; mi < 4; ++mi)
#pragma unroll
      for (int ni = 0; ni < 4; ++ni)
        acc[mi][ni] = __builtin_amdgcn_mfma_f32_16x16x32_f16(ah[mi], bh[ni], acc[mi][ni], 0, 0, 0);
    __builtin_amdgcn_s_setprio(0);
    __syncthreads();  // drains vmcnt (prefetch done) + everyone finished reading buf[cur]
    cur ^= 1;
  }

  float alpha = p.alphaMode ? __expf(p.log_beta[h]) : 1.0f;
  int om = (p.dual && job) ? p.outModeB : p.outMode;
  _Float16* c16 = (p.dual && job) ? p.C16b : p.C16;
  long long osR = (p.dual && job) ? p.cOsRb : p.cOsR;
  long long osC = (p.dual && job) ? p.cOsCb : p.cOsC;
  float* c32 = p.C32 + (p.nsplit > 1 ? (long long)ks * p.partStride : 0);
  long long cOff = (long long)bidx * p.cSB + (long long)h * p.cSH;
#pragma unroll
  for (int mi = 0; mi < 4; ++mi)
#pragma unroll
    for (int ni = 0; ni < 4; ++ni) {
      int row = m0 + wm + mi * 16 + quad * 4;
      int col = n0 + wn + ni * 16 + lr;
#pragma unroll
      for (int r = 0; r < 4; ++r) {
        float val = acc[mi][ni][r] * alpha;
        long long idx = cOff + (long long)(row + r) * osR + (long long)col * osC;
        if (om == 1) c32[idx] = val;
        else c16[idx] = (_Float16)val;
      }
    }
}

// 1-D flattened launch; optional XCD-chunked swizzle (grid must be divisible by 8).
template <int AMODE>
__global__ __launch_bounds__(256) void gemm_nt(GemmParams p) {
  int id = blockIdx.x;
  if (p.swz) {
    int q = (int)gridDim.x >> 3;
    id = (id & 7) * q + (id >> 3);
  }
  int bx = id % p.gx;
  int r = id / p.gx;
  gemm_body<AMODE>(p, bx, r % p.gy, r / p.gy);
}

// two independent AMODE-0 jobs in one launch (fills the machine, one less dispatch)
__global__ __launch_bounds__(256) void gemm_pair(GemmParams a, GemmParams b, int na) {
  int id = blockIdx.x;
  if (id < na) {
    int bx = id % a.gx;
    int r = id / a.gx;
    gemm_body<0>(a, bx, r % a.gy, r / a.gy);
  } else {
    int j = id - na;
    int bx = j % b.gx;
    int r = j / b.gx;
    gemm_body<0>(b, bx, r % b.gy, r / b.gy);
  }
}

// ---------------------------------------------------------------- host
extern "C" void kernel_launch(void* const* d_in, const int* in_sizes, int n_in,
                              void* d_out, int out_size, void* d_ws, size_t ws_size,
                              hipStream_t stream) {
  const float* hidden = (const float*)d_in[0];   // (2,1024,2048)
  const float* memory = (const float*)d_in[1];   // (2048,1024)
  const float* Wq = (const float*)d_in[2];       // (1024,2048)
  const float* Wk = (const float*)d_in[3];       // (1024,1024)
  const float* Wv = (const float*)d_in[4];       // (1024,1024)
  const float* Wo = (const float*)d_in[5];       // (2048,1024)
  const float* log_beta = (const float*)d_in[6]; // (8,)
  const float* g_state = (const float*)d_in[7];
  const float* b_state = (const float*)d_in[8];
  const float* g_mem = (const float*)d_in[9];
  const float* b_mem = (const float*)d_in[10];

  char* w = (char*)d_ws;
  auto alloc = [&](size_t bytes) {
    char* r = w;
    w += (bytes + 255) & ~(size_t)255;
    return r;
  };
  _Float16* wq16 = (_Float16*)alloc(2097152 * 2);
  _Float16* wk16 = (_Float16*)alloc(1048576 * 2);
  _Float16* wv16 = (_Float16*)alloc(1048576 * 2);
  _Float16* wo16 = (_Float16*)alloc(2097152 * 2);
  _Float16* lnh16 = (_Float16*)alloc(4194304 * 2);
  _Float16* mn16 = (_Float16*)alloc(2097152 * 2);
  _Float16* kph = (_Float16*)alloc(2097152 * 2);   // K proj (n, h*128+d)
  _Float16* vt16 = (_Float16*)alloc(2097152 * 2);  // V^T (h*128+d, n)
  _Float16* xih = (_Float16*)alloc(2097152 * 2);   // xi (b*S+s, h*128+d)
  float* parts = (float*)alloc((size_t)8 * 2097152 * 4);        // split-K partials
  _Float16* scores16 = (_Float16*)alloc((size_t)33554432 * 2);  // (b,h,s,n) fp16
  float* crow = (float*)alloc(16384 * 4);                       // per-row c = m/2 + tau

  ln_all<<<4096, 256, 0, stream>>>(hidden, memory, g_state, b_state, g_mem, b_mem, lnh16, mn16);
  cast_all<<<6144, 256, 0, stream>>>(Wq, wq16, Wk, wk16, Wv, wv16, Wo, wo16);

  // Q = ln(hidden) @ Wq^T  (split-K=2 partials)  +  K/V projections (dual)  in ONE launch
  {
    GemmParams pq{};
    pq.A = lnh16; pq.lda = 2048;
    pq.B = wq16; pq.ldb = 2048;
    pq.K = 2048; pq.nsplit = 2;
    pq.C32 = parts; pq.outMode = 1; pq.partStride = 2097152;
    pq.cOsR = 1024; pq.cOsC = 1;
    pq.gx = 16; pq.gy = 16;  // 256 blocks

    GemmParams pkv{};
    pkv.A = mn16; pkv.lda = 1024;
    pkv.B = wk16; pkv.B2 = wv16; pkv.ldb = 1024;
    pkv.K = 1024; pkv.dual = 1;
    pkv.C16 = kph; pkv.outMode = 0; pkv.cOsR = 1024; pkv.cOsC = 1;
    pkv.C16b = vt16; pkv.outModeB = 0; pkv.cOsRb = 1; pkv.cOsCb = 2048;
    pkv.gx = 8; pkv.gy = 16;  // gz=2 -> 256 blocks

    gemm_pair<<<512, 256, 0, stream>>>(pq, pkv, 256);
    reduce_split<<<2048, 256, 0, stream>>>(parts, 2, 2097152, xih, 2097152);
  }

  for (int step = 0; step < 3; ++step) {
    // scores = beta_h * xi @ K^T  (plain fp16, fp16 out)
    {
      GemmParams p{};
      p.A = xih;
      p.lda = 1024; p.aSB = 1048576; p.aSH = 128;
      p.B = kph; p.ldb = 1024; p.bSH = 128;
      p.K = 128;
      p.alphaMode = 1; p.log_beta = log_beta;
      p.C16 = scores16; p.outMode = 0;
      p.cSB = 16777216; p.cSH = 2097152;
      p.cOsR = 2048; p.cOsC = 1;
      p.gx = 16; p.gy = 8; p.swz = 1;  // 16*8*16 = 2048 blocks
      gemm_nt<0><<<2048, 256, 0, stream>>>(p);
    }
    entmax_c<<<4096, 256, 0, stream>>>(scores16, crow);
    // xi = w @ V  (w applied at frag-load from raw scores + crow, split-K=4 -> reduce)
    {
      GemmParams p{};
      p.A = scores16; p.crow = crow;
      p.lda = 2048; p.aSB = 16777216; p.aSH = 2097152;
      p.crowSB = 8192; p.crowSH = 1024;
      p.B = vt16; p.ldb = 2048; p.bSH = 262144;
      p.K = 2048; p.nsplit = 4;
      p.C32 = parts; p.outMode = 1; p.partStride = 2097152;
      p.cSB = 1048576; p.cSH = 128;
      p.cOsR = 1024; p.cOsC = 1;
      p.gx = 4; p.gy = 8; p.swz = 1;  // 4*8*16 = 512 blocks
      gemm_nt<1><<<512, 256, 0, stream>>>(p);
    }
    reduce_split<<<2048, 256, 0, stream>>>(parts, 4, 2097152, xih, 2097152);
  }

  // out = xi @ Wo^T  (fp32 out)
  {
    GemmParams p{};
    p.A = xih; p.lda = 1024;
    p.B = wo16; p.ldb = 1024;
    p.K = 1024;
    p.C32 = (float*)d_out; p.outMode = 1;
    p.cOsR = 2048; p.cOsC = 1;
    p.gx = 16; p.gy = 16; p.swz = 1;  // 256 blocks
    gemm_nt<0><<<256, 256, 0, stream>>>(p);
  }
}

// Round 2
// 424.169 us; speedup vs baseline: 1.1273x; 1.0006x over previous
//
#include <hip/hip_runtime.h>

typedef _Float16 half8 __attribute__((ext_vector_type(8)));
typedef _Float16 hv4 __attribute__((ext_vector_type(4)));
typedef float fv4 __attribute__((ext_vector_type(4)));

typedef __attribute__((address_space(3))) unsigned lds_u32;
typedef const __attribute__((address_space(1))) unsigned glb_u32;

// async global->LDS, 16B per lane; dst is wave-uniform base, HW adds lane*16B
__device__ __forceinline__ void gll16(const void* g, void* l) {
  __builtin_amdgcn_global_load_lds((glb_u32*)g, (lds_u32*)l, 16, 0, 0);
}

// ---------------------------------------------------------------- LayerNorm
__device__ __forceinline__ void ln_body(const float* __restrict__ in, const float* __restrict__ g,
                                        const float* __restrict__ bb, _Float16* __restrict__ out,
                                        int ncols, int row) {
  __shared__ float sm[8];
  int t = threadIdx.x;
  const float* rp = in + (size_t)row * ncols;
  int nv = ncols >> 10;
  fv4 v[2];
  float s1 = 0.f, s2 = 0.f;
#pragma unroll
  for (int c = 0; c < 2; ++c)
    if (c < nv) {
      v[c] = *(const fv4*)(rp + c * 1024 + t * 4);
#pragma unroll
      for (int j = 0; j < 4; ++j) { s1 += v[c][j]; s2 += v[c][j] * v[c][j]; }
    }
#pragma unroll
  for (int off = 32; off > 0; off >>= 1) { s1 += __shfl_xor(s1, off, 64); s2 += __shfl_xor(s2, off, 64); }
  int w = t >> 6;
  if ((t & 63) == 0) { sm[w] = s1; sm[4 + w] = s2; }
  __syncthreads();
  s1 = sm[0] + sm[1] + sm[2] + sm[3];
  s2 = sm[4] + sm[5] + sm[6] + sm[7];
  float inv = 1.0f / (float)ncols;
  float mu = s1 * inv;
  float var = s2 * inv - mu * mu;
  float rstd = rsqrtf(var + 1e-5f);
#pragma unroll
  for (int c = 0; c < 2; ++c)
    if (c < nv) {
      int col = c * 1024 + t * 4;
      fv4 gg = *(const fv4*)(g + col);
      fv4 bv = *(const fv4*)(bb + col);
      hv4 o;
#pragma unroll
      for (int j = 0; j < 4; ++j) o[j] = (_Float16)(((v[c][j] - mu) * rstd) * gg[j] + bv[j]);
      *(hv4*)(out + (size_t)row * ncols + col) = o;
    }
}

// merged: blocks [0,2048) -> hidden LN (2048 cols), [2048,4096) -> memory LN (1024 cols)
__global__ __launch_bounds__(256) void ln_all(const float* __restrict__ hid,
                                              const float* __restrict__ mem,
                                              const float* __restrict__ gs, const float* __restrict__ bs,
                                              const float* __restrict__ gm, const float* __restrict__ bm,
                                              _Float16* __restrict__ oh, _Float16* __restrict__ om) {
  int b = blockIdx.x;
  if (b < 2048) ln_body(hid, gs, bs, oh, 2048, b);
  else ln_body(mem, gm, bm, om, 1024, b - 2048);
}

// ---------------------------------------------------------------- merged fp32 -> fp16 casts
__global__ __launch_bounds__(256) void cast_all(const float* __restrict__ s0, _Float16* __restrict__ d0,
                                                const float* __restrict__ s1, _Float16* __restrict__ d1,
                                                const float* __restrict__ s2, _Float16* __restrict__ d2,
                                                const float* __restrict__ s3, _Float16* __restrict__ d3) {
  int b = blockIdx.x;
  const float* s;
  _Float16* d;
  int off;
  if (b < 2048) { s = s0; d = d0; off = b; }
  else if (b < 3072) { s = s1; d = d1; off = b - 2048; }
  else if (b < 4096) { s = s2; d = d2; off = b - 3072; }
  else { s = s3; d = d3; off = b - 4096; }
  int i = (off * 256 + threadIdx.x) << 2;
  fv4 f = *(const fv4*)(s + i);
  hv4 h;
#pragma unroll
  for (int j = 0; j < 4; ++j) h[j] = (_Float16)f[j];
  *(hv4*)(d + i) = h;
}

// ---------------------------------------------------------------- sum ns partials -> fp16
__global__ __launch_bounds__(256) void reduce_split(const float* __restrict__ parts, int ns,
                                                    long long stride,
                                                    _Float16* __restrict__ hi, int n) {
  int i = (blockIdx.x * 256 + threadIdx.x) << 2;
  if (i < n) {
    fv4 s = *(const fv4*)(parts + i);
    for (int j = 1; j < ns; ++j) {
      fv4 v = *(const fv4*)(parts + (size_t)j * stride + i);
      s += v;
    }
    hv4 h;
#pragma unroll
    for (int j = 0; j < 4; ++j) h[j] = (_Float16)s[j];
    *(hv4*)(hi + i) = h;
  }
}

// ---------------------------------------------------------------- entmax-1.5: tau solve only
__global__ __launch_bounds__(256) void entmax_c(const _Float16* __restrict__ scores,
                                                float* __restrict__ crow) {
  __shared__ float comp[4][512];
  int wid = threadIdx.x >> 6;
  int row = blockIdx.x * 4 + wid;
  int l = threadIdx.x & 63;
  unsigned long long lmask = (1ull << l) - 1ull;
  const half8* sp = (const half8*)(scores + (size_t)row * 2048);
  half8 hx[4];
#pragma unroll
  for (int i = 0; i < 4; ++i) hx[i] = sp[i * 64 + l];
  fv4 x[8];
#pragma unroll
  for (int i = 0; i < 4; ++i)
#pragma unroll
    for (int j = 0; j < 8; ++j) x[i * 2 + (j >> 2)][j & 3] = (float)hx[i][j];
  float m = x[0][0];
#pragma unroll
  for (int i = 0; i < 8; ++i)
#pragma unroll
    for (int j = 0; j < 4; ++j) m = fmaxf(m, x[i][j]);
#pragma unroll
  for (int off = 32; off > 0; off >>= 1) m = fmaxf(m, __shfl_xor(m, off, 64));
#pragma unroll
  for (int i = 0; i < 8; ++i)
#pragma unroll
    for (int j = 0; j < 4; ++j) x[i][j] = (x[i][j] - m) * 0.5f;

  float tau = -1.0f;
  bool fixed = false;
  int cnti = 2048;
  for (int it = 0; it < 6 && !fixed; ++it) {
    float s1 = 0.f, s2 = 0.f;
    cnti = 0;
#pragma unroll
    for (int i = 0; i < 8; ++i)
#pragma unroll
      for (int j = 0; j < 4; ++j) {
        bool a = x[i][j] > tau;
        cnti += (int)__builtin_popcountll(__ballot(a));
        float sel = a ? x[i][j] : 0.f;
        s1 += sel;
        s2 = fmaf(sel, sel, s2);
      }
#pragma unroll
    for (int off = 32; off > 0; off >>= 1) {
      s1 += __shfl_xor(s1, off, 64);
      s2 += __shfl_xor(s2, off, 64);
    }
    float cnt = (float)cnti;
    float mean = s1 / cnt;
    float ss = s2 - s1 * mean;
    float nt = mean - sqrtf(fmaxf((1.0f - ss) / cnt, 0.0f));
    if (nt == tau) fixed = true;
    else tau = nt;
    if (cnti <= 512) break;
  }
  if (!fixed) {
    if (cnti <= 512) {
      int base = 0;
#pragma unroll
      for (int i = 0; i < 8; ++i)
#pragma unroll
        for (int j = 0; j < 4; ++j) {
          bool a = x[i][j] > tau;
          unsigned long long mk = __ballot(a);
          if (a) comp[wid][base + (int)__builtin_popcountll(mk & lmask)] = x[i][j];
          base += (int)__builtin_popcountll(mk);
        }
      float y[8];
#pragma unroll
      for (int r = 0; r < 8; ++r) {
        int idx = r * 64 + l;
        y[r] = (idx < base) ? comp[wid][idx] : -2.0f;
      }
      for (int it = 0; it < 10 && !fixed; ++it) {
        float s1 = 0.f, s2 = 0.f;
        int c = 0;
#pragma unroll
        for (int r = 0; r < 8; ++r) {
          bool a = y[r] > tau;
          c += (int)__builtin_popcountll(__ballot(a));
          float sel = a ? y[r] : 0.f;
          s1 += sel;
          s2 = fmaf(sel, sel, s2);
        }
#pragma unroll
        for (int off = 32; off > 0; off >>= 1) {
          s1 += __shfl_xor(s1, off, 64);
          s2 += __shfl_xor(s2, off, 64);
        }
        float cnt = (float)c;
        float mean = s1 / cnt;
        float ss = s2 - s1 * mean;
        float nt = mean - sqrtf(fmaxf((1.0f - ss) / cnt, 0.0f));
        if (nt == tau) fixed = true;
        else tau = nt;
      }
    } else {
      for (int it = 0; it < 8 && !fixed; ++it) {
        float s1 = 0.f, s2 = 0.f;
        int c = 0;
#pragma unroll
        for (int i = 0; i < 8; ++i)
#pragma unroll
          for (int j = 0; j < 4; ++j) {
            bool a = x[i][j] > tau;
            c += (int)__builtin_popcountll(__ballot(a));
            float sel = a ? x[i][j] : 0.f;
            s1 += sel;
            s2 = fmaf(sel, sel, s2);
          }
#pragma unroll
        for (int off = 32; off > 0; off >>= 1) {
          s1 += __shfl_xor(s1, off, 64);
          s2 += __shfl_xor(s2, off, 64);
        }
        float cnt = (float)c;
        float mean = s1 / cnt;
        float ss = s2 - s1 * mean;
        float nt = mean - sqrtf(fmaxf((1.0f - ss) / cnt, 0.0f));
        if (nt == tau) fixed = true;
        else tau = nt;
      }
    }
  }

  if (l == 0) crow[row] = 0.5f * m + tau;
}

// ---------------------------------------------------------------- generic NT GEMM
// C[M,N] = alpha * A[M,K] @ B[N,K]^T.  128x128 tile, 4 waves, 4x4 16x16x32 f16 MFMA.
// 3-buffer LDS pipeline, prefetch depth 2, counted s_waitcnt vmcnt(4) + raw s_barrier
// (never drains the in-flight prefetch; T3/T4 minimum form).
// Chunk XOR-swizzle (T2, both-sides per rule #21): gll16 writes LDS linearly, so the
// swizzle is applied by permuting the GLOBAL source column-chunk in STAGE
// (chunk ^= (row>>1)&3) and the same XOR on the frag read (quad ^ (lr>>1)&3).
// Bank load per ds_read_b128 wave: uniform 8 dwords/bank (was 8-way on 8 banks).
// AMODE 0: plain fp16 A.   AMODE 1: w = (max(0, s/2 - c))^2 applied after frag read.
struct GemmParams {
  const _Float16 *A, *B, *B2;
  const float* crow;
  _Float16 *C16, *C16b;
  float* C32;
  const float* log_beta;
  int K, lda, ldb;
  long long aSB, aSH, bSH;
  long long crowSB, crowSH;
  long long cSB, cSH, cOsR, cOsC;
  long long cOsRb, cOsCb;
  long long partStride;
  int alphaMode, outMode, outModeB, nsplit, dual;
  int gx, gy, swz;
};

template <int AMODE>
__device__ __forceinline__ void gemm_body(const GemmParams& p, int bx, int by, int bz) {
  __shared__ __align__(16) _Float16 As[3][128 * 32];
  __shared__ __align__(16) _Float16 Bs[3][128 * 32];
  int t = threadIdx.x;
  int m0 = by * 128;
  int n0, kbeg, kend, ks = 0;
  if (p.nsplit > 1) {
    ks = bx % p.nsplit;
    n0 = (bx / p.nsplit) * 128;
    int kl = p.K / p.nsplit;
    kbeg = ks * kl;
    kend = kbeg + kl;
  } else {
    n0 = bx * 128;
    kbeg = 0;
    kend = p.K;
  }
  int bidx, h, job = 0;
  if (p.dual) { job = bz; bidx = 0; h = 0; }
  else { bidx = bz >> 3; h = bz & 7; }
  const _Float16* pA = p.A + bidx * p.aSB + h * p.aSH;
  const _Float16* pB = (job ? p.B2 : p.B) + h * p.bSH;

  fv4 acc[4][4] = {};
  int wv = t >> 6, l = t & 63, quad = l >> 4, lr = l & 15;
  int wm = (wv >> 1) * 64, wn = (wv & 1) * 64;
  int rl = l >> 2;                              // lane row-in-16 for staging
  int cs = (((l & 3) ^ ((l >> 3) & 3)) << 3);   // swizzled source chunk (halves)
  int rsw = (lr >> 1) & 3;                      // read-side XOR key

  float cr[4];
  if (AMODE == 1) {
    const float* pc = p.crow + bidx * p.crowSB + h * p.crowSH;
#pragma unroll
    for (int mi = 0; mi < 4; ++mi) cr[mi] = pc[m0 + wm + mi * 16 + lr];
    // drain so these never sit in the vmcnt FIFO the counted waits rely on
    asm volatile("s_waitcnt vmcnt(0)" ::: "memory");
  }

  auto STAGE = [&](int buf, int k0) {
#pragma unroll
    for (int v = 0; v < 2; ++v) {
      int rb = wv * 16 + v * 64;  // wave-uniform row base
      int r = rb + rl;
      gll16(pA + (size_t)(m0 + r) * p.lda + k0 + cs, &As[buf][rb * 32]);
      gll16(pB + (size_t)(n0 + r) * p.ldb + k0 + cs, &Bs[buf][rb * 32]);
    }
  };

  int nk = (kend - kbeg) >> 5;
  STAGE(0, kbeg);
  if (nk > 1) STAGE(1, kbeg + 32);
  int cur = 0;
  for (int ti = 0; ti < nk; ++ti) {
    // stage ti complete; stage ti+1 (4 gll16/wave) stays in flight
    if (ti + 1 < nk) asm volatile("s_waitcnt vmcnt(4)" ::: "memory");
    else asm volatile("s_waitcnt vmcnt(0)" ::: "memory");
    __builtin_amdgcn_s_barrier();  // also: all waves done reading buf[(ti+2)%3]
    __builtin_amdgcn_sched_barrier(0);
    if (ti + 2 < nk) {
      int nb = cur + 2;
      if (nb >= 3) nb -= 3;
      STAGE(nb, kbeg + ((ti + 2) << 5));
    }
    __builtin_amdgcn_sched_barrier(0);
    half8 ah[4], bh[4];
#pragma unroll
    for (int mi = 0; mi < 4; ++mi) {
      half8 a = *(const half8*)&As[cur][(wm + mi * 16 + lr) * 32 + ((quad ^ rsw) << 3)];
      if (AMODE == 1) {
        half8 d = a * (_Float16)0.5f - (_Float16)cr[mi];  // v_pk_fma (scalar splat)
        d = __builtin_elementwise_max(d, (half8)(0));     // v_pk_max_f16
        a = d * d;                                        // v_pk_mul_f16
      }
      ah[mi] = a;
    }
#pragma unroll
    for (int ni = 0; ni < 4; ++ni)
      bh[ni] = *(const half8*)&Bs[cur][(wn + ni * 16 + lr) * 32 + ((quad ^ rsw) << 3)];
    __builtin_amdgcn_s_setprio(1);
#pragma unroll
    for (int mi = 0; mi < 4; ++mi)
#pragma unroll
      for (int ni = 0; ni < 4; ++ni)
        acc[mi][ni] = __builtin_amdgcn_mfma_f32_16x16x32_f16(ah[mi], bh[ni], acc[mi][ni], 0, 0, 0);
    __builtin_amdgcn_s_setprio(0);
    cur = (cur == 2) ? 0 : cur + 1;
  }

  float alpha = p.alphaMode ? __expf(p.log_beta[h]) : 1.0f;
  int om = (p.dual && job) ? p.outModeB : p.outMode;
  _Float16* c16 = (p.dual && job) ? p.C16b : p.C16;
  long long osR = (p.dual && job) ? p.cOsRb : p.cOsR;
  long long osC = (p.dual && job) ? p.cOsCb : p.cOsC;
  float* c32 = p.C32 + (p.nsplit > 1 ? (long long)ks * p.partStride : 0);
  long long cOff = (long long)bidx * p.cSB + (long long)h * p.cSH;
#pragma unroll
  for (int mi = 0; mi < 4; ++mi)
#pragma unroll
    for (int ni = 0; ni < 4; ++ni) {
      int row = m0 + wm + mi * 16 + quad * 4;
      int col = n0 + wn + ni * 16 + lr;
#pragma unroll
      for (int r = 0; r < 4; ++r) {
        float val = acc[mi][ni][r] * alpha;
        long long idx = cOff + (long long)(row + r) * osR + (long long)col * osC;
        if (om == 1) c32[idx] = val;
        else c16[idx] = (_Float16)val;
      }
    }
}

// 1-D flattened launch; optional XCD-chunked swizzle (grid must be divisible by 8).
template <int AMODE>
__global__ __launch_bounds__(256) void gemm_nt(GemmParams p) {
  int id = blockIdx.x;
  if (p.swz) {
    int q = (int)gridDim.x >> 3;
    id = (id & 7) * q + (id >> 3);
  }
  int bx = id % p.gx;
  int r = id / p.gx;
  gemm_body<AMODE>(p, bx, r % p.gy, r / p.gy);
}

// two independent AMODE-0 jobs in one launch
__global__ __launch_bounds__(256) void gemm_pair(GemmParams a, GemmParams b, int na) {
  int id = blockIdx.x;
  if (id < na) {
    int bx = id % a.gx;
    int r = id / a.gx;
    gemm_body<0>(a, bx, r % a.gy, r / a.gy);
  } else {
    int j = id - na;
    int bx = j % b.gx;
    int r = j / b.gx;
    gemm_body<0>(b, bx, r % b.gy, r / b.gy);
  }
}

// ---------------------------------------------------------------- host
extern "C" void kernel_launch(void* const* d_in, const int* in_sizes, int n_in,
                              void* d_out, int out_size, void* d_ws, size_t ws_size,
                              hipStream_t stream) {
  const float* hidden = (const float*)d_in[0];   // (2,1024,2048)
  const float* memory = (const float*)d_in[1];   // (2048,1024)
  const float* Wq = (const float*)d_in[2];       // (1024,2048)
  const float* Wk = (const float*)d_in[3];       // (1024,1024)
  const float* Wv = (const float*)d_in[4];       // (1024,1024)
  const float* Wo = (const float*)d_in[5];       // (2048,1024)
  const float* log_beta = (const float*)d_in[6]; // (8,)
  const float* g_state = (const float*)d_in[7];
  const float* b_state = (const float*)d_in[8];
  const float* g_mem = (const float*)d_in[9];
  const float* b_mem = (const float*)d_in[10];

  char* w = (char*)d_ws;
  auto alloc = [&](size_t bytes) {
    char* r = w;
    w += (bytes + 255) & ~(size_t)255;
    return r;
  };
  _Float16* wq16 = (_Float16*)alloc(2097152 * 2);
  _Float16* wk16 = (_Float16*)alloc(1048576 * 2);
  _Float16* wv16 = (_Float16*)alloc(1048576 * 2);
  _Float16* wo16 = (_Float16*)alloc(2097152 * 2);
  _Float16* lnh16 = (_Float16*)alloc(4194304 * 2);
  _Float16* mn16 = (_Float16*)alloc(2097152 * 2);
  _Float16* kph = (_Float16*)alloc(2097152 * 2);   // K proj (n, h*128+d)
  _Float16* vt16 = (_Float16*)alloc(2097152 * 2);  // V^T (h*128+d, n)
  _Float16* xih = (_Float16*)alloc(2097152 * 2);   // xi (b*S+s, h*128+d)
  float* parts = (float*)alloc((size_t)8 * 2097152 * 4);        // split-K partials
  _Float16* scores16 = (_Float16*)alloc((size_t)33554432 * 2);  // (b,h,s,n) fp16
  float* crow = (float*)alloc(16384 * 4);                       // per-row c = m/2 + tau

  ln_all<<<4096, 256, 0, stream>>>(hidden, memory, g_state, b_state, g_mem, b_mem, lnh16, mn16);
  cast_all<<<6144, 256, 0, stream>>>(Wq, wq16, Wk, wk16, Wv, wv16, Wo, wo16);

  // Q = ln(hidden) @ Wq^T (split-K=2) + K/V projections (dual) in ONE launch
  {
    GemmParams pq{};
    pq.A = lnh16; pq.lda = 2048;
    pq.B = wq16; pq.ldb = 2048;
    pq.K = 2048; pq.nsplit = 2;
    pq.C32 = parts; pq.outMode = 1; pq.partStride = 2097152;
    pq.cOsR = 1024; pq.cOsC = 1;
    pq.gx = 16; pq.gy = 16;  // 256 blocks

    GemmParams pkv{};
    pkv.A = mn16; pkv.lda = 1024;
    pkv.B = wk16; pkv.B2 = wv16; pkv.ldb = 1024;
    pkv.K = 1024; pkv.dual = 1;
    pkv.C16 = kph; pkv.outMode = 0; pkv.cOsR = 1024; pkv.cOsC = 1;
    pkv.C16b = vt16; pkv.outModeB = 0; pkv.cOsRb = 1; pkv.cOsCb = 2048;
    pkv.gx = 8; pkv.gy = 16;  // gz=2 -> 256 blocks

    gemm_pair<<<512, 256, 0, stream>>>(pq, pkv, 256);
    reduce_split<<<2048, 256, 0, stream>>>(parts, 2, 2097152, xih, 2097152);
  }

  for (int step = 0; step < 3; ++step) {
    // scores = beta_h * xi @ K^T
    {
      GemmParams p{};
      p.A = xih;
      p.lda = 1024; p.aSB = 1048576; p.aSH = 128;
      p.B = kph; p.ldb = 1024; p.bSH = 128;
      p.K = 128;
      p.alphaMode = 1; p.log_beta = log_beta;
      p.C16 = scores16; p.outMode = 0;
      p.cSB = 16777216; p.cSH = 2097152;
      p.cOsR = 2048; p.cOsC = 1;
      p.gx = 16; p.gy = 8; p.swz = 1;  // 2048 blocks
      gemm_nt<0><<<2048, 256, 0, stream>>>(p);
    }
    entmax_c<<<4096, 256, 0, stream>>>(scores16, crow);
    // xi = w @ V  (w applied at frag-load, split-K=4 -> reduce)
    {
      GemmParams p{};
      p.A = scores16; p.crow = crow;
      p.lda = 2048; p.aSB = 16777216; p.aSH = 2097152;
      p.crowSB = 8192; p.crowSH = 1024;
      p.B = vt16; p.ldb = 2048; p.bSH = 262144;
      p.K = 2048; p.nsplit = 4;
      p.C32 = parts; p.outMode = 1; p.partStride = 2097152;
      p.cSB = 1048576; p.cSH = 128;
      p.cOsR = 1024; p.cOsC = 1;
      p.gx = 4; p.gy = 8; p.swz = 1;  // 512 blocks
      gemm_nt<1><<<512, 256, 0, stream>>>(p);
    }
    reduce_split<<<2048, 256, 0, stream>>>(parts, 4, 2097152, xih, 2097152);
  }

  // out = xi @ Wo^T  (fp32 out)
  {
    GemmParams p{};
    p.A = xih; p.lda = 1024;
    p.B = wo16; p.ldb = 1024;
    p.K = 1024;
    p.C32 = (float*)d_out; p.outMode = 1;
    p.cOsR = 2048; p.cOsC = 1;
    p.gx = 16; p.gy = 16; p.swz = 1;  // 256 blocks
    gemm_nt<0><<<256, 256, 0, stream>>>(p);
  }
}